// Round 1
// baseline (873.431 us; speedup 1.0000x reference)
//
#include <hip/hip_runtime.h>

// ---------------------------------------------------------------------------
// GraphSAGE (2x SAGEConv mean + mean-pool + MLP scorer), f32 end-to-end.
// Strategy: build CSR (edges sorted by dst) once with int atomics, then both
// aggregation passes are atomic-free coalesced gathers (wave per dst node).
// ---------------------------------------------------------------------------

__global__ void k_deg(const int* __restrict__ dst, int* __restrict__ deg, int E) {
    int e = blockIdx.x * 256 + threadIdx.x;
    if (e < E) atomicAdd(&deg[dst[e]], 1);
}

// block-level exclusive scan (1024/block), writes per-element exclusive + block sum
__global__ void k_scan1(const int* __restrict__ deg, int* __restrict__ rp,
                        int* __restrict__ bsum, int n) {
    __shared__ int sm[1024];
    int i = blockIdx.x * 1024 + threadIdx.x;
    int v = (i < n) ? deg[i] : 0;
    sm[threadIdx.x] = v;
    __syncthreads();
    for (int off = 1; off < 1024; off <<= 1) {
        int t = (threadIdx.x >= off) ? sm[threadIdx.x - off] : 0;
        __syncthreads();
        sm[threadIdx.x] += t;
        __syncthreads();
    }
    if (i < n) rp[i] = sm[threadIdx.x] - v;   // exclusive within block
    if (threadIdx.x == 1023) bsum[blockIdx.x] = sm[1023];
}

// scan the (<=1024) block sums in one block -> exclusive
__global__ void k_scan2(int* __restrict__ bsum, int nb) {
    __shared__ int sm[1024];
    int t = threadIdx.x;
    int v = (t < nb) ? bsum[t] : 0;
    sm[t] = v;
    __syncthreads();
    for (int off = 1; off < 1024; off <<= 1) {
        int u = (t >= off) ? sm[t - off] : 0;
        __syncthreads();
        sm[t] += u;
        __syncthreads();
    }
    if (t < nb) bsum[t] = sm[t] - v;          // exclusive block offsets
}

// add block offsets; also produce deg_inv, zero the scatter counters, set rp[n]=E
__global__ void k_scan3(int* __restrict__ rp, const int* __restrict__ bsum,
                        const int* __restrict__ deg, float* __restrict__ dinv,
                        int* __restrict__ cnt, int n, int E) {
    int i = blockIdx.x * 1024 + threadIdx.x;
    if (i < n) {
        rp[i] += bsum[blockIdx.x];
        int d = deg[i];
        dinv[i] = (d > 0) ? 1.0f / (float)d : 0.0f;
        cnt[i] = 0;
    }
    if (i == 0) rp[n] = E;
}

__global__ void k_scatter(const int* __restrict__ src, const int* __restrict__ dst,
                          const int* __restrict__ rp, int* __restrict__ cnt,
                          int* __restrict__ ssrc, int E) {
    int e = blockIdx.x * 256 + threadIdx.x;
    if (e >= E) return;
    int d = dst[e];
    int pos = rp[d] + atomicAdd(&cnt[d], 1);
    ssrc[pos] = src[e];
}

// h0[n][0:32] = emb[node_ids[n]][0:32]; 8 threads (float4 each) per node
__global__ void k_emb(const int* __restrict__ ids, const float* __restrict__ emb,
                      float* __restrict__ h0, int n) {
    int t = blockIdx.x * 256 + threadIdx.x;
    int node = t >> 3, q = t & 7;
    if (node >= n) return;
    size_t id = (size_t)ids[node];
    *(float4*)(h0 + (size_t)node * 32 + q * 4) =
        *(const float4*)(emb + id * 32 + q * 4);
}

// mean-aggregate 32-wide rows: one wave per dst node, 8 edges x 8 lanes(float4)
__global__ void k_agg32(const float* __restrict__ h, const int* __restrict__ rp,
                        const int* __restrict__ ssrc, const float* __restrict__ dinv,
                        float* __restrict__ agg, int n) {
    int wid = (blockIdx.x * 256 + threadIdx.x) >> 6;
    int lane = threadIdx.x & 63;
    if (wid >= n) return;
    int start = rp[wid], end = rp[wid + 1];
    int eo = lane >> 3, q = lane & 7;
    float4 acc = {0.f, 0.f, 0.f, 0.f};
    for (int e = start + eo; e < end; e += 8) {
        int s = ssrc[e];
        float4 v = *(const float4*)(h + (size_t)s * 32 + q * 4);
        acc.x += v.x; acc.y += v.y; acc.z += v.z; acc.w += v.w;
    }
    for (int m = 8; m < 64; m <<= 1) {
        acc.x += __shfl_xor(acc.x, m);
        acc.y += __shfl_xor(acc.y, m);
        acc.z += __shfl_xor(acc.z, m);
        acc.w += __shfl_xor(acc.w, m);
    }
    if (lane < 8) {
        float di = dinv[wid];
        float4 o = {acc.x * di, acc.y * di, acc.z * di, acc.w * di};
        *(float4*)(agg + (size_t)wid * 32 + q * 4) = o;
    }
}

// mean-aggregate 64-wide rows: one wave per dst node, 4 edges x 16 lanes(float4)
__global__ void k_agg64(const float* __restrict__ h, const int* __restrict__ rp,
                        const int* __restrict__ ssrc, const float* __restrict__ dinv,
                        float* __restrict__ agg, int n) {
    int wid = (blockIdx.x * 256 + threadIdx.x) >> 6;
    int lane = threadIdx.x & 63;
    if (wid >= n) return;
    int start = rp[wid], end = rp[wid + 1];
    int eo = lane >> 4, q = lane & 15;
    float4 acc = {0.f, 0.f, 0.f, 0.f};
    for (int e = start + eo; e < end; e += 4) {
        int s = ssrc[e];
        float4 v = *(const float4*)(h + (size_t)s * 64 + q * 4);
        acc.x += v.x; acc.y += v.y; acc.z += v.z; acc.w += v.w;
    }
    for (int m = 16; m < 64; m <<= 1) {
        acc.x += __shfl_xor(acc.x, m);
        acc.y += __shfl_xor(acc.y, m);
        acc.z += __shfl_xor(acc.z, m);
        acc.w += __shfl_xor(acc.w, m);
    }
    if (lane < 16) {
        float di = dinv[wid];
        float4 o = {acc.x * di, acc.y * di, acc.z * di, acc.w * di};
        *(float4*)(agg + (size_t)wid * 64 + q * 4) = o;
    }
}

// out[n][64] = relu(x[n][:K] @ Ws + a[n][:K] @ Wn + b); thread = node.
// Weights staged in LDS (uniform-address broadcast reads). jt loop kept runtime
// to bound I-cache footprint; k loop fully unrolled (static reg indexing).
template <int K>
__global__ __launch_bounds__(256) void k_dense(
    const float* __restrict__ x, const float* __restrict__ a,
    const float* __restrict__ Wsg, const float* __restrict__ Wng,
    const float* __restrict__ bg, float* __restrict__ out, int n) {
    __shared__ float ws[K * 64];
    __shared__ float wn[K * 64];
    __shared__ float bs[64];
    for (int i = threadIdx.x; i < K * 64; i += 256) { ws[i] = Wsg[i]; wn[i] = Wng[i]; }
    if (threadIdx.x < 64) bs[threadIdx.x] = bg[threadIdx.x];
    __syncthreads();
    int node = blockIdx.x * 256 + threadIdx.x;
    if (node >= n) return;
    float xr[K], ar[K];
#pragma unroll
    for (int q = 0; q < K / 4; ++q) {
        float4 v = *(const float4*)(x + (size_t)node * K + q * 4);
        xr[q * 4 + 0] = v.x; xr[q * 4 + 1] = v.y; xr[q * 4 + 2] = v.z; xr[q * 4 + 3] = v.w;
        float4 u = *(const float4*)(a + (size_t)node * K + q * 4);
        ar[q * 4 + 0] = u.x; ar[q * 4 + 1] = u.y; ar[q * 4 + 2] = u.z; ar[q * 4 + 3] = u.w;
    }
    float* op = out + (size_t)node * 64;
#pragma unroll 1
    for (int jt = 0; jt < 8; ++jt) {
        float acc0 = bs[jt * 8 + 0], acc1 = bs[jt * 8 + 1], acc2 = bs[jt * 8 + 2], acc3 = bs[jt * 8 + 3];
        float acc4 = bs[jt * 8 + 4], acc5 = bs[jt * 8 + 5], acc6 = bs[jt * 8 + 6], acc7 = bs[jt * 8 + 7];
#pragma unroll
        for (int k = 0; k < K; ++k) {
            float4 w0 = *(const float4*)&ws[k * 64 + jt * 8];
            float4 w1 = *(const float4*)&ws[k * 64 + jt * 8 + 4];
            acc0 += xr[k] * w0.x; acc1 += xr[k] * w0.y; acc2 += xr[k] * w0.z; acc3 += xr[k] * w0.w;
            acc4 += xr[k] * w1.x; acc5 += xr[k] * w1.y; acc6 += xr[k] * w1.z; acc7 += xr[k] * w1.w;
            float4 v0 = *(const float4*)&wn[k * 64 + jt * 8];
            float4 v1 = *(const float4*)&wn[k * 64 + jt * 8 + 4];
            acc0 += ar[k] * v0.x; acc1 += ar[k] * v0.y; acc2 += ar[k] * v0.z; acc3 += ar[k] * v0.w;
            acc4 += ar[k] * v1.x; acc5 += ar[k] * v1.y; acc6 += ar[k] * v1.z; acc7 += ar[k] * v1.w;
        }
        float4 o0 = {fmaxf(acc0, 0.f), fmaxf(acc1, 0.f), fmaxf(acc2, 0.f), fmaxf(acc3, 0.f)};
        float4 o1 = {fmaxf(acc4, 0.f), fmaxf(acc5, 0.f), fmaxf(acc6, 0.f), fmaxf(acc7, 0.f)};
        *(float4*)(op + jt * 8) = o0;
        *(float4*)(op + jt * 8 + 4) = o1;
    }
}

// graph boundaries via binary search (graph_ids is sorted)
__global__ void k_bounds(const int* __restrict__ gid, int* __restrict__ starts,
                         int n, int B) {
    int b = blockIdx.x * 256 + threadIdx.x;
    if (b > B) return;
    if (b == B) { starts[B] = n; return; }
    int lo = 0, hi = n;
    while (lo < hi) {
        int mid = (lo + hi) >> 1;
        if (gid[mid] < b) lo = mid + 1; else hi = mid;
    }
    starts[b] = lo;
}

// per-graph mean over node range; block per graph, 4 rows x 64 feats
__global__ void k_pool(const float* __restrict__ h2, const int* __restrict__ starts,
                       float* __restrict__ hg, int B) {
    __shared__ float sm[256];
    int b = blockIdx.x;
    int t = threadIdx.x, j = t & 63, r = t >> 6;
    int s = starts[b], e = starts[b + 1];
    float acc = 0.f;
    for (int nn = s + r; nn < e; nn += 4) acc += h2[(size_t)nn * 64 + j];
    sm[t] = acc;
    __syncthreads();
    if (t < 64) {
        float v = sm[t] + sm[t + 64] + sm[t + 128] + sm[t + 192];
        float cntf = (float)(e - s);
        hg[b * 64 + j] = v / fmaxf(cntf, 1.0f);
    }
}

// scorer: relu(hg @ Ws1 + bs1) @ Ws2 + bs2 ; block per graph, 64 lanes
__global__ void k_score(const float* __restrict__ hg, const float* __restrict__ Ws1,
                        const float* __restrict__ bs1, const float* __restrict__ Ws2,
                        const float* __restrict__ bs2, float* __restrict__ out, int B) {
    int b = blockIdx.x;
    int j = threadIdx.x;  // 64 threads
    const float* hrow = hg + b * 64;
    float acc = bs1[j];
    for (int k = 0; k < 64; ++k) acc += hrow[k] * Ws1[k * 64 + j];
    float t = fmaxf(acc, 0.f) * Ws2[j];
    for (int m = 1; m < 64; m <<= 1) t += __shfl_xor(t, m);
    if (j == 0) out[b] = t + bs2[0];
}

extern "C" void kernel_launch(void* const* d_in, const int* in_sizes, int n_in,
                              void* d_out, int out_size, void* d_ws, size_t ws_size,
                              hipStream_t stream) {
    const int*   node_ids = (const int*)d_in[0];
    const int*   src      = (const int*)d_in[1];
    const int*   dst      = (const int*)d_in[2];
    const int*   gid      = (const int*)d_in[3];
    const float* emb      = (const float*)d_in[4];
    const float* Ws1      = (const float*)d_in[5];
    const float* Wn1      = (const float*)d_in[6];
    const float* b1       = (const float*)d_in[7];
    const float* Ws2      = (const float*)d_in[8];
    const float* Wn2      = (const float*)d_in[9];
    const float* b2       = (const float*)d_in[10];
    const float* Ms1      = (const float*)d_in[11];
    const float* mb1      = (const float*)d_in[12];
    const float* Ms2      = (const float*)d_in[13];
    const float* mb2      = (const float*)d_in[14];
    float* out = (float*)d_out;

    int N = in_sizes[0];
    int E = in_sizes[1];
    int B = out_size;

    char* w = (char*)d_ws;
    size_t off = 0;
    auto take = [&](size_t bytes) -> void* {
        void* p = (void*)(w + off);
        off += (bytes + 255) & ~(size_t)255;
        return p;
    };
    int*   deg    = (int*)take((size_t)N * 4);
    int*   rp     = (int*)take((size_t)(N + 1) * 4);
    int*   cnt    = (int*)take((size_t)N * 4);
    int*   bsum   = (int*)take(1024 * 4);
    float* dinv   = (float*)take((size_t)N * 4);
    int*   ssrc   = (int*)take((size_t)E * 4);
    float* h0     = (float*)take((size_t)N * 64 * 4);   // layer-1 input (stride 32), reused as h2 (stride 64)
    float* h1     = (float*)take((size_t)N * 64 * 4);
    float* agg    = (float*)take((size_t)N * 64 * 4);   // reused: stride 32 then 64
    int*   starts = (int*)take((size_t)(B + 1) * 4);
    float* hg     = (float*)take((size_t)B * 64 * 4);

    hipMemsetAsync(deg, 0, (size_t)N * 4, stream);

    int nb = (N + 1023) / 1024;
    k_deg<<<(E + 255) / 256, 256, 0, stream>>>(dst, deg, E);
    k_scan1<<<nb, 1024, 0, stream>>>(deg, rp, bsum, N);
    k_scan2<<<1, 1024, 0, stream>>>(bsum, nb);
    k_scan3<<<nb, 1024, 0, stream>>>(rp, bsum, deg, dinv, cnt, N, E);
    k_scatter<<<(E + 255) / 256, 256, 0, stream>>>(src, dst, rp, cnt, ssrc, E);

    k_emb<<<(N * 8 + 255) / 256, 256, 0, stream>>>(node_ids, emb, h0, N);

    // layer 1: agg over h0 (32-wide), dense 32->64
    k_agg32<<<(N + 3) / 4, 256, 0, stream>>>(h0, rp, ssrc, dinv, agg, N);
    k_dense<32><<<(N + 255) / 256, 256, 0, stream>>>(h0, agg, Ws1, Wn1, b1, h1, N);

    // layer 2: agg over h1 (64-wide), dense 64->64 (h2 reuses h0 buffer)
    k_agg64<<<(N + 3) / 4, 256, 0, stream>>>(h1, rp, ssrc, dinv, agg, N);
    k_dense<64><<<(N + 255) / 256, 256, 0, stream>>>(h1, agg, Ws2, Wn2, b2, h0, N);

    // pooling + scorer
    k_bounds<<<(B + 1 + 255) / 256, 256, 0, stream>>>(gid, starts, N, B);
    k_pool<<<B, 256, 0, stream>>>(h0, starts, hg, B);
    k_score<<<B, 64, 0, stream>>>(hg, Ms1, mb1, Ms2, mb2, out, B);
}

// Round 3
// 735.786 us; speedup vs baseline: 1.1871x; 1.1871x over previous
//
#include <hip/hip_runtime.h>

// ---------------------------------------------------------------------------
// GraphSAGE (2x SAGEConv mean + mean-pool + MLP scorer), f32 end-to-end.
// CSR build via two-level counting sort (bucket = dst>>8) so every scatter
// write has line locality: writeback ~= useful bytes (was 16x amplified).
// Aggregation passes are atomic-free coalesced gathers (wave per dst node).
// ---------------------------------------------------------------------------

#define EPB 16384  // edges per block in binning kernels

// per-block LDS histogram of bucket sizes -> global bucket counts
__global__ __launch_bounds__(256) void k_bcnt(const int* __restrict__ dst,
                                              int* __restrict__ bcnt, int E) {
    __shared__ int hist[1024];
    for (int i = threadIdx.x; i < 1024; i += 256) hist[i] = 0;
    __syncthreads();
    int s = blockIdx.x * EPB;
    int e_end = min(s + EPB, E);
    for (int e = s + threadIdx.x; e < e_end; e += 256)
        atomicAdd(&hist[dst[e] >> 8], 1);
    __syncthreads();
    for (int i = threadIdx.x; i < 1024; i += 256)
        if (hist[i]) atomicAdd(&bcnt[i], hist[i]);
}

// exclusive scan of bucket counts (NB <= 1024) -> bbase, and mutable btail copy
__global__ void k_bscan(const int* __restrict__ bcnt, int* __restrict__ bbase,
                        int* __restrict__ btail, int NB) {
    __shared__ int sm[1024];
    int t = threadIdx.x;
    int v = (t < NB) ? bcnt[t] : 0;
    sm[t] = v;
    __syncthreads();
    for (int off = 1; off < 1024; off <<= 1) {
        int u = (t >= off) ? sm[t - off] : 0;
        __syncthreads();
        sm[t] += u;
        __syncthreads();
    }
    if (t < NB) { int ex = sm[t] - v; bbase[t] = ex; btail[t] = ex; }
}

// bin (src,dst) pairs into bucket regions; per-block LDS count -> one global
// atomic per (block,bucket) -> appending, line-local writes
__global__ __launch_bounds__(256) void k_binscatter(
    const int* __restrict__ src, const int* __restrict__ dst,
    int* __restrict__ btail, int2* __restrict__ pairs, int E) {
    __shared__ int hist[1024];
    __shared__ int base[1024];
    int s = blockIdx.x * EPB;
    int e_end = min(s + EPB, E);
    for (int i = threadIdx.x; i < 1024; i += 256) hist[i] = 0;
    __syncthreads();
    for (int e = s + threadIdx.x; e < e_end; e += 256)
        atomicAdd(&hist[dst[e] >> 8], 1);
    __syncthreads();
    for (int i = threadIdx.x; i < 1024; i += 256) {
        int h = hist[i];
        base[i] = h ? atomicAdd(&btail[i], h) : 0;
        hist[i] = 0;  // reuse as local append counter
    }
    __syncthreads();
    for (int e = s + threadIdx.x; e < e_end; e += 256) {
        int d = dst[e];
        int b = d >> 8;
        int pos = base[b] + atomicAdd(&hist[b], 1);
        pairs[pos] = make_int2(src[e], d);
    }
}

// per-bucket LDS histogram -> deg + dinv, no global atomics
__global__ __launch_bounds__(256) void k_hist(
    const int2* __restrict__ pairs, const int* __restrict__ bbase,
    const int* __restrict__ bcnt, int* __restrict__ deg,
    float* __restrict__ dinv, int N) {
    __shared__ int h[256];
    int b = blockIdx.x, t = threadIdx.x;
    h[t] = 0;
    __syncthreads();
    int s = bbase[b], cntb = bcnt[b];
    for (int i = t; i < cntb; i += 256)
        atomicAdd(&h[pairs[s + i].y & 255], 1);
    __syncthreads();
    int node = b * 256 + t;
    if (node < N) {
        int d = h[t];
        deg[node] = d;
        dinv[node] = (d > 0) ? 1.0f / (float)d : 0.0f;
    }
}

// block-level exclusive scan (1024/block) of deg -> rp partial + block sums
__global__ void k_scan1(const int* __restrict__ deg, int* __restrict__ rp,
                        int* __restrict__ bsum, int n) {
    __shared__ int sm[1024];
    int i = blockIdx.x * 1024 + threadIdx.x;
    int v = (i < n) ? deg[i] : 0;
    sm[threadIdx.x] = v;
    __syncthreads();
    for (int off = 1; off < 1024; off <<= 1) {
        int t = (threadIdx.x >= off) ? sm[threadIdx.x - off] : 0;
        __syncthreads();
        sm[threadIdx.x] += t;
        __syncthreads();
    }
    if (i < n) rp[i] = sm[threadIdx.x] - v;
    if (threadIdx.x == 1023) bsum[blockIdx.x] = sm[1023];
}

__global__ void k_scan2(int* __restrict__ bsum, int nb) {
    __shared__ int sm[1024];
    int t = threadIdx.x;
    int v = (t < nb) ? bsum[t] : 0;
    sm[t] = v;
    __syncthreads();
    for (int off = 1; off < 1024; off <<= 1) {
        int u = (t >= off) ? sm[t - off] : 0;
        __syncthreads();
        sm[t] += u;
        __syncthreads();
    }
    if (t < nb) bsum[t] = sm[t] - v;
}

__global__ void k_scan3(int* __restrict__ rp, const int* __restrict__ bsum,
                        int n, int E) {
    int i = blockIdx.x * 1024 + threadIdx.x;
    if (i < n) rp[i] += bsum[blockIdx.x];
    if (i == 0) rp[n] = E;
}

// per-bucket final placement: all writes land in the bucket's ~16KB CSR range
__global__ __launch_bounds__(256) void k_localsort(
    const int2* __restrict__ pairs, const int* __restrict__ bbase,
    const int* __restrict__ bcnt, const int* __restrict__ rp,
    int* __restrict__ ssrc, int N) {
    __shared__ int lrp[256];
    __shared__ int lcnt[256];
    int b = blockIdx.x, t = threadIdx.x;
    int node = b * 256 + t;
    lrp[t] = (node < N) ? rp[node] : 0;
    lcnt[t] = 0;
    __syncthreads();
    int s = bbase[b], cntb = bcnt[b];
    for (int i = t; i < cntb; i += 256) {
        int2 p = pairs[s + i];
        int local = p.y & 255;
        int pos = lrp[local] + atomicAdd(&lcnt[local], 1);
        ssrc[pos] = p.x;
    }
}

// h0[n][0:32] = emb[node_ids[n]][0:32]; 8 threads (float4 each) per node
__global__ void k_emb(const int* __restrict__ ids, const float* __restrict__ emb,
                      float* __restrict__ h0, int n) {
    int t = blockIdx.x * 256 + threadIdx.x;
    int node = t >> 3, q = t & 7;
    if (node >= n) return;
    size_t id = (size_t)ids[node];
    *(float4*)(h0 + (size_t)node * 32 + q * 4) =
        *(const float4*)(emb + id * 32 + q * 4);
}

// mean-aggregate 32-wide rows: one wave per dst node, 8 edges x 8 lanes(float4)
__global__ void k_agg32(const float* __restrict__ h, const int* __restrict__ rp,
                        const int* __restrict__ ssrc, const float* __restrict__ dinv,
                        float* __restrict__ agg, int n) {
    int wid = (blockIdx.x * 256 + threadIdx.x) >> 6;
    int lane = threadIdx.x & 63;
    if (wid >= n) return;
    int start = rp[wid], end = rp[wid + 1];
    int eo = lane >> 3, q = lane & 7;
    float4 acc = {0.f, 0.f, 0.f, 0.f};
    for (int e = start + eo; e < end; e += 8) {
        int s = ssrc[e];
        float4 v = *(const float4*)(h + (size_t)s * 32 + q * 4);
        acc.x += v.x; acc.y += v.y; acc.z += v.z; acc.w += v.w;
    }
    for (int m = 8; m < 64; m <<= 1) {
        acc.x += __shfl_xor(acc.x, m);
        acc.y += __shfl_xor(acc.y, m);
        acc.z += __shfl_xor(acc.z, m);
        acc.w += __shfl_xor(acc.w, m);
    }
    if (lane < 8) {
        float di = dinv[wid];
        float4 o = {acc.x * di, acc.y * di, acc.z * di, acc.w * di};
        *(float4*)(agg + (size_t)wid * 32 + q * 4) = o;
    }
}

// mean-aggregate 64-wide rows: one wave per dst node, 4 edges x 16 lanes(float4)
__global__ void k_agg64(const float* __restrict__ h, const int* __restrict__ rp,
                        const int* __restrict__ ssrc, const float* __restrict__ dinv,
                        float* __restrict__ agg, int n) {
    int wid = (blockIdx.x * 256 + threadIdx.x) >> 6;
    int lane = threadIdx.x & 63;
    if (wid >= n) return;
    int start = rp[wid], end = rp[wid + 1];
    int eo = lane >> 4, q = lane & 15;
    float4 acc = {0.f, 0.f, 0.f, 0.f};
    for (int e = start + eo; e < end; e += 4) {
        int s = ssrc[e];
        float4 v = *(const float4*)(h + (size_t)s * 64 + q * 4);
        acc.x += v.x; acc.y += v.y; acc.z += v.z; acc.w += v.w;
    }
    for (int m = 16; m < 64; m <<= 1) {
        acc.x += __shfl_xor(acc.x, m);
        acc.y += __shfl_xor(acc.y, m);
        acc.z += __shfl_xor(acc.z, m);
        acc.w += __shfl_xor(acc.w, m);
    }
    if (lane < 16) {
        float di = dinv[wid];
        float4 o = {acc.x * di, acc.y * di, acc.z * di, acc.w * di};
        *(float4*)(agg + (size_t)wid * 64 + q * 4) = o;
    }
}

// out[n][64] = relu(x[n][:K] @ Ws + a[n][:K] @ Wn + b); thread = node.
template <int K>
__global__ __launch_bounds__(256) void k_dense(
    const float* __restrict__ x, const float* __restrict__ a,
    const float* __restrict__ Wsg, const float* __restrict__ Wng,
    const float* __restrict__ bg, float* __restrict__ out, int n) {
    __shared__ float ws[K * 64];
    __shared__ float wn[K * 64];
    __shared__ float bs[64];
    for (int i = threadIdx.x; i < K * 64; i += 256) { ws[i] = Wsg[i]; wn[i] = Wng[i]; }
    if (threadIdx.x < 64) bs[threadIdx.x] = bg[threadIdx.x];
    __syncthreads();
    int node = blockIdx.x * 256 + threadIdx.x;
    if (node >= n) return;
    float xr[K], ar[K];
#pragma unroll
    for (int q = 0; q < K / 4; ++q) {
        float4 v = *(const float4*)(x + (size_t)node * K + q * 4);
        xr[q * 4 + 0] = v.x; xr[q * 4 + 1] = v.y; xr[q * 4 + 2] = v.z; xr[q * 4 + 3] = v.w;
        float4 u = *(const float4*)(a + (size_t)node * K + q * 4);
        ar[q * 4 + 0] = u.x; ar[q * 4 + 1] = u.y; ar[q * 4 + 2] = u.z; ar[q * 4 + 3] = u.w;
    }
    float* op = out + (size_t)node * 64;
#pragma unroll 1
    for (int jt = 0; jt < 8; ++jt) {
        float acc0 = bs[jt * 8 + 0], acc1 = bs[jt * 8 + 1], acc2 = bs[jt * 8 + 2], acc3 = bs[jt * 8 + 3];
        float acc4 = bs[jt * 8 + 4], acc5 = bs[jt * 8 + 5], acc6 = bs[jt * 8 + 6], acc7 = bs[jt * 8 + 7];
#pragma unroll
        for (int k = 0; k < K; ++k) {
            float4 w0 = *(const float4*)&ws[k * 64 + jt * 8];
            float4 w1 = *(const float4*)&ws[k * 64 + jt * 8 + 4];
            acc0 += xr[k] * w0.x; acc1 += xr[k] * w0.y; acc2 += xr[k] * w0.z; acc3 += xr[k] * w0.w;
            acc4 += xr[k] * w1.x; acc5 += xr[k] * w1.y; acc6 += xr[k] * w1.z; acc7 += xr[k] * w1.w;
            float4 v0 = *(const float4*)&wn[k * 64 + jt * 8];
            float4 v1 = *(const float4*)&wn[k * 64 + jt * 8 + 4];
            acc0 += ar[k] * v0.x; acc1 += ar[k] * v0.y; acc2 += ar[k] * v0.z; acc3 += ar[k] * v0.w;
            acc4 += ar[k] * v1.x; acc5 += ar[k] * v1.y; acc6 += ar[k] * v1.z; acc7 += ar[k] * v1.w;
        }
        float4 o0 = {fmaxf(acc0, 0.f), fmaxf(acc1, 0.f), fmaxf(acc2, 0.f), fmaxf(acc3, 0.f)};
        float4 o1 = {fmaxf(acc4, 0.f), fmaxf(acc5, 0.f), fmaxf(acc6, 0.f), fmaxf(acc7, 0.f)};
        *(float4*)(op + jt * 8) = o0;
        *(float4*)(op + jt * 8 + 4) = o1;
    }
}

// graph boundaries via binary search (graph_ids is sorted)
__global__ void k_bounds(const int* __restrict__ gid, int* __restrict__ starts,
                         int n, int B) {
    int b = blockIdx.x * 256 + threadIdx.x;
    if (b > B) return;
    if (b == B) { starts[B] = n; return; }
    int lo = 0, hi = n;
    while (lo < hi) {
        int mid = (lo + hi) >> 1;
        if (gid[mid] < b) lo = mid + 1; else hi = mid;
    }
    starts[b] = lo;
}

// per-graph mean over node range; block per graph, 4 rows x 64 feats
__global__ void k_pool(const float* __restrict__ h2, const int* __restrict__ starts,
                       float* __restrict__ hg, int B) {
    __shared__ float sm[256];
    int b = blockIdx.x;
    int t = threadIdx.x, j = t & 63, r = t >> 6;
    int s = starts[b], e = starts[b + 1];
    float acc = 0.f;
    for (int nn = s + r; nn < e; nn += 4) acc += h2[(size_t)nn * 64 + j];
    sm[t] = acc;
    __syncthreads();
    if (t < 64) {
        float v = sm[t] + sm[t + 64] + sm[t + 128] + sm[t + 192];
        float cntf = (float)(e - s);
        hg[b * 64 + j] = v / fmaxf(cntf, 1.0f);
    }
}

// scorer: relu(hg @ Ws1 + bs1) @ Ws2 + bs2 ; block per graph, 64 lanes
__global__ void k_score(const float* __restrict__ hg, const float* __restrict__ Ws1,
                        const float* __restrict__ bs1, const float* __restrict__ Ws2,
                        const float* __restrict__ bs2, float* __restrict__ out, int B) {
    int b = blockIdx.x;
    int j = threadIdx.x;  // 64 threads
    const float* hrow = hg + b * 64;
    float acc = bs1[j];
    for (int k = 0; k < 64; ++k) acc += hrow[k] * Ws1[k * 64 + j];
    float t = fmaxf(acc, 0.f) * Ws2[j];
    for (int m = 1; m < 64; m <<= 1) t += __shfl_xor(t, m);
    if (j == 0) out[b] = t + bs2[0];
}

extern "C" void kernel_launch(void* const* d_in, const int* in_sizes, int n_in,
                              void* d_out, int out_size, void* d_ws, size_t ws_size,
                              hipStream_t stream) {
    const int*   node_ids = (const int*)d_in[0];
    const int*   src      = (const int*)d_in[1];
    const int*   dst      = (const int*)d_in[2];
    const int*   gid      = (const int*)d_in[3];
    const float* emb      = (const float*)d_in[4];
    const float* Ws1      = (const float*)d_in[5];
    const float* Wn1      = (const float*)d_in[6];
    const float* b1       = (const float*)d_in[7];
    const float* Ws2      = (const float*)d_in[8];
    const float* Wn2      = (const float*)d_in[9];
    const float* b2       = (const float*)d_in[10];
    const float* Ms1      = (const float*)d_in[11];
    const float* mb1      = (const float*)d_in[12];
    const float* Ms2      = (const float*)d_in[13];
    const float* mb2      = (const float*)d_in[14];
    float* out = (float*)d_out;

    int N = in_sizes[0];
    int E = in_sizes[1];
    int B = out_size;
    int NB = (N + 255) >> 8;          // dst buckets (<=1024)

    char* w = (char*)d_ws;
    size_t off = 0;
    auto take = [&](size_t bytes) -> void* {
        void* p = (void*)(w + off);
        off += (bytes + 255) & ~(size_t)255;
        return p;
    };
    int*   deg    = (int*)take((size_t)N * 4);
    int*   rp     = (int*)take((size_t)(N + 1) * 4);
    int*   bsum   = (int*)take(1024 * 4);
    float* dinv   = (float*)take((size_t)N * 4);
    int*   ssrc   = (int*)take((size_t)E * 4);
    int*   bcnt   = (int*)take(1024 * 4);
    int*   bbase  = (int*)take(1024 * 4);
    int*   btail  = (int*)take(1024 * 4);
    float* h0     = (float*)take((size_t)N * 64 * 4);   // layer-1 input (stride 32), reused as h2 (stride 64)
    float* h1     = (float*)take((size_t)N * 64 * 4);
    float* agg    = (float*)take((size_t)N * 64 * 4);   // reused: stride 32 then 64
    int*   starts = (int*)take((size_t)(B + 1) * 4);
    float* hg     = (float*)take((size_t)B * 64 * 4);
    int2*  pairs  = (int2*)agg;       // alias: pairs dead before k_agg32 writes agg

    int nbeb = (E + EPB - 1) / EPB;
    int nb = (N + 1023) / 1024;

    hipMemsetAsync(bcnt, 0, (size_t)NB * 4, stream);
    k_bcnt<<<nbeb, 256, 0, stream>>>(dst, bcnt, E);
    k_bscan<<<1, 1024, 0, stream>>>(bcnt, bbase, btail, NB);
    k_binscatter<<<nbeb, 256, 0, stream>>>(src, dst, btail, pairs, E);
    k_hist<<<NB, 256, 0, stream>>>(pairs, bbase, bcnt, deg, dinv, N);
    k_scan1<<<nb, 1024, 0, stream>>>(deg, rp, bsum, N);
    k_scan2<<<1, 1024, 0, stream>>>(bsum, nb);
    k_scan3<<<nb, 1024, 0, stream>>>(rp, bsum, N, E);
    k_localsort<<<NB, 256, 0, stream>>>(pairs, bbase, bcnt, rp, ssrc, N);

    k_emb<<<(N * 8 + 255) / 256, 256, 0, stream>>>(node_ids, emb, h0, N);

    // layer 1: agg over h0 (32-wide), dense 32->64
    k_agg32<<<(N + 3) / 4, 256, 0, stream>>>(h0, rp, ssrc, dinv, agg, N);
    k_dense<32><<<(N + 255) / 256, 256, 0, stream>>>(h0, agg, Ws1, Wn1, b1, h1, N);

    // layer 2: agg over h1 (64-wide), dense 64->64 (h2 reuses h0 buffer)
    k_agg64<<<(N + 3) / 4, 256, 0, stream>>>(h1, rp, ssrc, dinv, agg, N);
    k_dense<64><<<(N + 255) / 256, 256, 0, stream>>>(h1, agg, Ws2, Wn2, b2, h0, N);

    // pooling + scorer
    k_bounds<<<(B + 1 + 255) / 256, 256, 0, stream>>>(gid, starts, N, B);
    k_pool<<<B, 256, 0, stream>>>(h0, starts, hg, B);
    k_score<<<B, 64, 0, stream>>>(hg, Ms1, mb1, Ms2, mb2, out, B);
}